// Round 1
// baseline (304.187 us; speedup 1.0000x reference)
//
#include <hip/hip_runtime.h>
#include <cstdint>

typedef unsigned short ushort_t;
typedef __bf16 bf16x8 __attribute__((ext_vector_type(8)));
typedef float f32x4 __attribute__((ext_vector_type(4)));

#define B_ 8
#define T_ 2048
#define D_ 1024
#define M_ (B_ * T_)        // 16384
#define NCHUNK 32
#define CHUNKLEN 64         // 32*64 = 2048 = T_

__device__ __forceinline__ ushort_t f2bf(float f) {
    union { float f; uint32_t u; } v; v.f = f;
    uint32_t u = v.u;
    uint32_t r = (u + 0x7fffu + ((u >> 16) & 1u)) >> 16;
    return (ushort_t)r;
}
__device__ __forceinline__ float bf2f(ushort_t h) {
    union { uint32_t u; float f; } v; v.u = ((uint32_t)h) << 16;
    return v.f;
}

__device__ __forceinline__ void async16(const ushort_t* g, ushort_t* l) {
    __builtin_amdgcn_global_load_lds(
        (const __attribute__((address_space(1))) void*)g,
        (__attribute__((address_space(3))) void*)l, 16, 0, 0);
}

// ---------------- cast fp32 -> bf16 (4 elems/thread) ----------------
__global__ __launch_bounds__(256) void cast_bf16(const float* __restrict__ src,
                                                 ushort_t* __restrict__ dst, int n4) {
    int i = blockIdx.x * blockDim.x + threadIdx.x;
    if (i < n4) {
        float4 v = ((const float4*)src)[i];
        ushort4 o;
        o.x = f2bf(v.x); o.y = f2bf(v.y); o.z = f2bf(v.z); o.w = f2bf(v.w);
        ((ushort4*)dst)[i] = o;
    }
}

// ---------------- fused QKV GEMM (m97 structure) ----------------
// C[m][n] = sum_k x[m][k] * W[n][k] + bias[n]
// grid (M/128, 24); blockIdx.y: w = y>>3 selects {q,k,v}, n0 = (y&7)*128
__global__ __launch_bounds__(256) void qkv_gemm(
    const ushort_t* __restrict__ xb, const ushort_t* __restrict__ Wb,
    const float* __restrict__ bq, const float* __restrict__ bk,
    const float* __restrict__ bv,
    float* __restrict__ qout, ushort_t* __restrict__ kbf, ushort_t* __restrict__ vbf) {
    __shared__ ushort_t As[128 * 32];
    __shared__ ushort_t Bs[128 * 32];

    const int mb = blockIdx.x, nb = blockIdx.y;
    const int w = nb >> 3;
    const int m0 = mb * 128, n0 = (nb & 7) * 128;
    const ushort_t* Wsrc = Wb + (size_t)w * D_ * D_;

    const int t = threadIdx.x;
    const int lane = t & 63, wv = t >> 6;
    const int wr = (wv >> 1) * 64, wc = (wv & 1) * 64;

    f32x4 acc[4][4];
#pragma unroll
    for (int i = 0; i < 4; ++i)
#pragma unroll
        for (int j = 0; j < 4; ++j) acc[i][j] = (f32x4){0.f, 0.f, 0.f, 0.f};

    // staging: thread t covers 16B chunks idx=t and idx=t+256 of each 8 KB tile
    const int r0 = t >> 2, r1 = (t + 256) >> 2;
    const int c0 = (t & 3) * 8;

    const int ka = (lane >> 4) * 8;
    const int rowa = wr + (lane & 15);
    const int rowb = wc + (lane & 15);

    for (int kt = 0; kt < 32; ++kt) {
        const int k0 = kt * 32;
        async16(xb + (size_t)(m0 + r0) * D_ + k0 + c0, &As[t * 8]);
        async16(xb + (size_t)(m0 + r1) * D_ + k0 + c0, &As[(t + 256) * 8]);
        async16(Wsrc + (size_t)(n0 + r0) * D_ + k0 + c0, &Bs[t * 8]);
        async16(Wsrc + (size_t)(n0 + r1) * D_ + k0 + c0, &Bs[(t + 256) * 8]);
        __syncthreads();

        bf16x8 af[4], bfr[4];
#pragma unroll
        for (int i = 0; i < 4; ++i)
            af[i] = *(const bf16x8*)&As[(rowa + i * 16) * 32 + ka];
#pragma unroll
        for (int j = 0; j < 4; ++j)
            bfr[j] = *(const bf16x8*)&Bs[(rowb + j * 16) * 32 + ka];
#pragma unroll
        for (int i = 0; i < 4; ++i)
#pragma unroll
            for (int j = 0; j < 4; ++j)
                acc[i][j] = __builtin_amdgcn_mfma_f32_16x16x32_bf16(
                    af[i], bfr[j], acc[i][j], 0, 0, 0);
        __syncthreads();
    }

    // epilogue: C/D layout col=lane&15, row=(lane>>4)*4+r
    const float* bias = (w == 0) ? bq : ((w == 1) ? bk : bv);
    const int colq = lane & 15;
    const int rowq = (lane >> 4) * 4;
#pragma unroll
    for (int i = 0; i < 4; ++i) {
#pragma unroll
        for (int j = 0; j < 4; ++j) {
            const int cg = n0 + wc + j * 16 + colq;
            const float bval = bias[cg];
#pragma unroll
            for (int r = 0; r < 4; ++r) {
                const int rg = m0 + wr + i * 16 + rowq + r;
                const float val = acc[i][j][r] + bval;
                const size_t off = (size_t)rg * D_ + cg;
                if (w == 0)      qout[off] = val;
                else if (w == 1) kbf[off] = f2bf(val);
                else             vbf[off] = f2bf(val);
            }
        }
    }
}

// ---------------- scan pass 1: per-chunk local scan -> chunk sum ----------------
// grid = B_*NCHUNK blocks, 1024 threads (d)
__global__ __launch_bounds__(1024) void scan_chunks(
    const ushort_t* __restrict__ kb, const ushort_t* __restrict__ vb,
    const float* __restrict__ decay, float* __restrict__ S) {
    const int b = blockIdx.x >> 5, c = blockIdx.x & 31;
    const int d = threadIdx.x;
    const float dec = decay[d];
    float m = 0.f;
    size_t base = ((size_t)b * T_ + c * CHUNKLEN) * D_ + d;
#pragma unroll 8
    for (int i = 0; i < CHUNKLEN; ++i) {
        const size_t o = base + (size_t)i * D_;
        m = fmaf(dec, m, bf2f(kb[o]) * bf2f(vb[o]));
    }
    S[((size_t)b * NCHUNK + c) * D_ + d] = m;
}

// ---------------- scan pass 2: carry scan across chunks ----------------
// one thread per (b,d): 8192 threads
__global__ __launch_bounds__(256) void scan_carry(
    const float* __restrict__ S, const float* __restrict__ decay,
    float* __restrict__ P) {
    const int idx = blockIdx.x * blockDim.x + threadIdx.x;
    const int d = idx & (D_ - 1), b = idx >> 10;
    const float dec = decay[d];
    float dL = dec;
    dL *= dL; dL *= dL; dL *= dL; dL *= dL; dL *= dL; dL *= dL;  // dec^64
    float p = 0.f;
    for (int c = 0; c < NCHUNK; ++c) {
        const size_t o = ((size_t)b * NCHUNK + c) * D_ + d;
        P[o] = p;
        p = fmaf(dL, p, S[o]);
    }
}

// ---------------- scan pass 3: replay with carry, out = q * mem ----------------
__global__ __launch_bounds__(1024) void scan_final(
    const ushort_t* __restrict__ kb, const ushort_t* __restrict__ vb,
    const float* __restrict__ decay, const float* __restrict__ P,
    float* __restrict__ out) {
    const int b = blockIdx.x >> 5, c = blockIdx.x & 31;
    const int d = threadIdx.x;
    const float dec = decay[d];
    float m = P[((size_t)b * NCHUNK + c) * D_ + d];
    size_t base = ((size_t)b * T_ + c * CHUNKLEN) * D_ + d;
#pragma unroll 8
    for (int i = 0; i < CHUNKLEN; ++i) {
        const size_t o = base + (size_t)i * D_;
        m = fmaf(dec, m, bf2f(kb[o]) * bf2f(vb[o]));
        out[o] = out[o] * m;  // out holds q from the GEMM
    }
}

extern "C" void kernel_launch(void* const* d_in, const int* in_sizes, int n_in,
                              void* d_out, int out_size, void* d_ws, size_t ws_size,
                              hipStream_t stream) {
    const float* x     = (const float*)d_in[0];
    const float* Wq    = (const float*)d_in[1];
    const float* bq    = (const float*)d_in[2];
    const float* Wk    = (const float*)d_in[3];
    const float* bk    = (const float*)d_in[4];
    const float* Wv    = (const float*)d_in[5];
    const float* bv    = (const float*)d_in[6];
    const float* decay = (const float*)d_in[7];
    float* out = (float*)d_out;

    // workspace carve (109 MB total)
    char* ws = (char*)d_ws;
    ushort_t* xb  = (ushort_t*)(ws);                        // 33,554,432 B
    ushort_t* Wb  = (ushort_t*)(ws + 33554432);             //  6,291,456 B
    ushort_t* kbf = (ushort_t*)(ws + 39845888);             // 33,554,432 B
    ushort_t* vbf = (ushort_t*)(ws + 73400320);             // 33,554,432 B
    float*    S   = (float*)(ws + 106954752);               //  1,048,576 B
    float*    P   = (float*)(ws + 108003328);               //  1,048,576 B

    // casts
    cast_bf16<<<(M_ * D_ / 4 + 255) / 256, 256, 0, stream>>>(x, xb, M_ * D_ / 4);
    cast_bf16<<<(D_ * D_ / 4 + 255) / 256, 256, 0, stream>>>(Wq, Wb, D_ * D_ / 4);
    cast_bf16<<<(D_ * D_ / 4 + 255) / 256, 256, 0, stream>>>(Wk, Wb + D_ * D_, D_ * D_ / 4);
    cast_bf16<<<(D_ * D_ / 4 + 255) / 256, 256, 0, stream>>>(Wv, Wb + 2 * D_ * D_, D_ * D_ / 4);

    // fused QKV GEMM: q -> d_out (fp32), k/v -> ws (bf16)
    dim3 g(M_ / 128, 24);
    qkv_gemm<<<g, 256, 0, stream>>>(xb, Wb, bq, bk, bv, out, kbf, vbf);

    // chunked diagonal-decay scan
    scan_chunks<<<B_ * NCHUNK, 1024, 0, stream>>>(kbf, vbf, decay, S);
    scan_carry<<<(B_ * D_) / 256, 256, 0, stream>>>(S, decay, P);
    scan_final<<<B_ * NCHUNK, 1024, 0, stream>>>(kbf, vbf, decay, P, out);
}

// Round 2
// 289.578 us; speedup vs baseline: 1.0504x; 1.0504x over previous
//
#include <hip/hip_runtime.h>
#include <cstdint>

typedef unsigned short ushort_t;
typedef __bf16 bf16x8 __attribute__((ext_vector_type(8)));
typedef float f32x4 __attribute__((ext_vector_type(4)));

#define B_ 8
#define T_ 2048
#define D_ 1024
#define M_ (B_ * T_)        // 16384
#define NCHUNK 64
#define CHUNKLEN 32         // 64*32 = 2048 = T_

__device__ __forceinline__ ushort_t f2bf(float f) {
    union { float f; uint32_t u; } v; v.f = f;
    uint32_t u = v.u;
    uint32_t r = (u + 0x7fffu + ((u >> 16) & 1u)) >> 16;
    return (ushort_t)r;
}
__device__ __forceinline__ float bf2f(ushort_t h) {
    union { uint32_t u; float f; } v; v.u = ((uint32_t)h) << 16;
    return v.f;
}

__device__ __forceinline__ void async16(const ushort_t* g, ushort_t* l) {
    __builtin_amdgcn_global_load_lds(
        (const __attribute__((address_space(1))) void*)g,
        (__attribute__((address_space(3))) void*)l, 16, 0, 0);
}

// ---------------- cast fp32 -> bf16 for x ----------------
__global__ __launch_bounds__(256) void cast_bf16(const float* __restrict__ src,
                                                 ushort_t* __restrict__ dst, int n4) {
    int i = blockIdx.x * blockDim.x + threadIdx.x;
    if (i < n4) {
        float4 v = ((const float4*)src)[i];
        ushort4 o;
        o.x = f2bf(v.x); o.y = f2bf(v.y); o.z = f2bf(v.z); o.w = f2bf(v.w);
        ((ushort4*)dst)[i] = o;
    }
}

// ---------------- cast all three W matrices in one launch ----------------
__global__ __launch_bounds__(256) void cast_w3(const float* __restrict__ wq,
                                               const float* __restrict__ wk,
                                               const float* __restrict__ wv,
                                               ushort_t* __restrict__ dst) {
    const int n4 = D_ * D_ / 4;  // 262144 float4 per matrix
    int i = blockIdx.x * blockDim.x + threadIdx.x;  // 0 .. 3*n4-1
    const float* src = (i < n4) ? wq : ((i < 2 * n4) ? wk : wv);
    int li = (i < n4) ? i : ((i < 2 * n4) ? i - n4 : i - 2 * n4);
    float4 v = ((const float4*)src)[li];
    ushort4 o;
    o.x = f2bf(v.x); o.y = f2bf(v.y); o.z = f2bf(v.z); o.w = f2bf(v.w);
    ((ushort4*)(dst))[i] = o;
}

// ============ GEMM Q: C = x @ Wq^T + bq -> bf16 qb ============
// Bank-conflict-free LDS: global chunk c of row r lands at LDS slot c^((r>>1)&3).
__global__ __launch_bounds__(256) void gemm_q(
    const ushort_t* __restrict__ xb, const ushort_t* __restrict__ Wq,
    const float* __restrict__ bq, ushort_t* __restrict__ qb) {
    __shared__ ushort_t As[128 * 32];
    __shared__ ushort_t Bs[128 * 32];

    const int m0 = blockIdx.x * 128, n0 = blockIdx.y * 128;
    const int t = threadIdx.x;
    const int lane = t & 63, wv = t >> 6;
    const int wr = (wv >> 1) * 64, wc = (wv & 1) * 64;

    f32x4 acc[4][4];
#pragma unroll
    for (int i = 0; i < 4; ++i)
#pragma unroll
        for (int j = 0; j < 4; ++j) acc[i][j] = (f32x4){0.f, 0.f, 0.f, 0.f};

    const int r0 = t >> 2, r1 = r0 + 64;
    const int sc = ((t & 3) ^ ((r0 >> 1) & 3)) * 8;   // swizzled source col (elements)

    const int swq = ((lane & 15) >> 1) & 3;
    const int csel = (((lane >> 4) ^ swq)) * 8;       // swizzled LDS col (elements)
    const int rowa = wr + (lane & 15);
    const int rowb = wc + (lane & 15);

    for (int kt = 0; kt < 32; ++kt) {
        const int k0 = kt * 32;
        async16(xb + (size_t)(m0 + r0) * D_ + k0 + sc, &As[t * 8]);
        async16(xb + (size_t)(m0 + r1) * D_ + k0 + sc, &As[(t + 256) * 8]);
        async16(Wq + (size_t)(n0 + r0) * D_ + k0 + sc, &Bs[t * 8]);
        async16(Wq + (size_t)(n0 + r1) * D_ + k0 + sc, &Bs[(t + 256) * 8]);
        __syncthreads();

        bf16x8 af[4], bfr[4];
#pragma unroll
        for (int i = 0; i < 4; ++i)
            af[i] = *(const bf16x8*)&As[(rowa + i * 16) * 32 + csel];
#pragma unroll
        for (int j = 0; j < 4; ++j)
            bfr[j] = *(const bf16x8*)&Bs[(rowb + j * 16) * 32 + csel];
#pragma unroll
        for (int i = 0; i < 4; ++i)
#pragma unroll
            for (int j = 0; j < 4; ++j)
                acc[i][j] = __builtin_amdgcn_mfma_f32_16x16x32_bf16(
                    af[i], bfr[j], acc[i][j], 0, 0, 0);
        __syncthreads();
    }

    const int colq = lane & 15;
    const int rowq = (lane >> 4) * 4;
#pragma unroll
    for (int i = 0; i < 4; ++i) {
#pragma unroll
        for (int j = 0; j < 4; ++j) {
            const int cg = n0 + wc + j * 16 + colq;
            const float bval = bq[cg];
#pragma unroll
            for (int r = 0; r < 4; ++r) {
                const int rg = m0 + wr + i * 16 + rowq + r;
                qb[(size_t)rg * D_ + cg] = f2bf(acc[i][j][r] + bval);
            }
        }
    }
}

// ============ GEMM KV: kv = (x@Wk^T+bk) * (x@Wv^T+bv) -> bf16 kvb ============
__global__ __launch_bounds__(256, 2) void gemm_kv(
    const ushort_t* __restrict__ xb, const ushort_t* __restrict__ Wk,
    const ushort_t* __restrict__ Wv, const float* __restrict__ bk,
    const float* __restrict__ bv, ushort_t* __restrict__ kvb) {
    __shared__ ushort_t As[128 * 32];
    __shared__ ushort_t Bk[128 * 32];
    __shared__ ushort_t Bv[128 * 32];

    const int m0 = blockIdx.x * 128, n0 = blockIdx.y * 128;
    const int t = threadIdx.x;
    const int lane = t & 63, wv = t >> 6;
    const int wr = (wv >> 1) * 64, wc = (wv & 1) * 64;

    f32x4 acck[4][4], accv[4][4];
#pragma unroll
    for (int i = 0; i < 4; ++i)
#pragma unroll
        for (int j = 0; j < 4; ++j) {
            acck[i][j] = (f32x4){0.f, 0.f, 0.f, 0.f};
            accv[i][j] = (f32x4){0.f, 0.f, 0.f, 0.f};
        }

    const int r0 = t >> 2, r1 = r0 + 64;
    const int sc = ((t & 3) ^ ((r0 >> 1) & 3)) * 8;

    const int swq = ((lane & 15) >> 1) & 3;
    const int csel = (((lane >> 4) ^ swq)) * 8;
    const int rowa = wr + (lane & 15);
    const int rowb = wc + (lane & 15);

    for (int kt = 0; kt < 32; ++kt) {
        const int k0 = kt * 32;
        async16(xb + (size_t)(m0 + r0) * D_ + k0 + sc, &As[t * 8]);
        async16(xb + (size_t)(m0 + r1) * D_ + k0 + sc, &As[(t + 256) * 8]);
        async16(Wk + (size_t)(n0 + r0) * D_ + k0 + sc, &Bk[t * 8]);
        async16(Wk + (size_t)(n0 + r1) * D_ + k0 + sc, &Bk[(t + 256) * 8]);
        async16(Wv + (size_t)(n0 + r0) * D_ + k0 + sc, &Bv[t * 8]);
        async16(Wv + (size_t)(n0 + r1) * D_ + k0 + sc, &Bv[(t + 256) * 8]);
        __syncthreads();

        bf16x8 af[4], bk8[4], bv8[4];
#pragma unroll
        for (int i = 0; i < 4; ++i)
            af[i] = *(const bf16x8*)&As[(rowa + i * 16) * 32 + csel];
#pragma unroll
        for (int j = 0; j < 4; ++j) {
            bk8[j] = *(const bf16x8*)&Bk[(rowb + j * 16) * 32 + csel];
            bv8[j] = *(const bf16x8*)&Bv[(rowb + j * 16) * 32 + csel];
        }
#pragma unroll
        for (int i = 0; i < 4; ++i)
#pragma unroll
            for (int j = 0; j < 4; ++j) {
                acck[i][j] = __builtin_amdgcn_mfma_f32_16x16x32_bf16(
                    af[i], bk8[j], acck[i][j], 0, 0, 0);
                accv[i][j] = __builtin_amdgcn_mfma_f32_16x16x32_bf16(
                    af[i], bv8[j], accv[i][j], 0, 0, 0);
            }
        __syncthreads();
    }

    const int colq = lane & 15;
    const int rowq = (lane >> 4) * 4;
#pragma unroll
    for (int i = 0; i < 4; ++i) {
#pragma unroll
        for (int j = 0; j < 4; ++j) {
            const int cg = n0 + wc + j * 16 + colq;
            const float bkv = bk[cg], bvv = bv[cg];
#pragma unroll
            for (int r = 0; r < 4; ++r) {
                const int rg = m0 + wr + i * 16 + rowq + r;
                const float kf = acck[i][j][r] + bkv;
                const float vf = accv[i][j][r] + bvv;
                kvb[(size_t)rg * D_ + cg] = f2bf(kf * vf);
            }
        }
    }
}

// ---------------- scan pass 1: per-chunk local scan -> chunk sum ----------------
// block: 256 threads, 2 channels each (512 d). grid = B_*NCHUNK*2 = 1024.
__global__ __launch_bounds__(256) void scan_chunks(
    const ushort_t* __restrict__ kvb, const float* __restrict__ decay,
    float* __restrict__ S) {
    const int b = blockIdx.x >> 7;
    const int c = (blockIdx.x >> 1) & 63;
    const int dg = blockIdx.x & 1;
    const int d0 = dg * 512 + threadIdx.x * 2;
    const float dc0 = decay[d0], dc1 = decay[d0 + 1];
    float m0 = 0.f, m1 = 0.f;
    size_t base = ((size_t)b * T_ + c * CHUNKLEN) * D_ + d0;
#pragma unroll 8
    for (int i = 0; i < CHUNKLEN; ++i) {
        ushort2 kv = *(const ushort2*)&kvb[base + (size_t)i * D_];
        m0 = fmaf(dc0, m0, bf2f(kv.x));
        m1 = fmaf(dc1, m1, bf2f(kv.y));
    }
    float2* so = (float2*)&S[((size_t)b * NCHUNK + c) * D_ + d0];
    *so = make_float2(m0, m1);
}

// ---------------- scan pass 2: carry scan across chunks ----------------
__global__ __launch_bounds__(256) void scan_carry(
    const float* __restrict__ S, const float* __restrict__ decay,
    float* __restrict__ P) {
    const int idx = blockIdx.x * blockDim.x + threadIdx.x;  // 8192
    const int d = idx & (D_ - 1), b = idx >> 10;
    const float dec = decay[d];
    float dL = dec;
    dL *= dL; dL *= dL; dL *= dL; dL *= dL; dL *= dL;  // dec^32
    float p = 0.f;
    for (int c = 0; c < NCHUNK; ++c) {
        const size_t o = ((size_t)b * NCHUNK + c) * D_ + d;
        P[o] = p;
        p = fmaf(dL, p, S[o]);
    }
}

// ---------------- scan pass 3: replay with carry, out = q * mem ----------------
__global__ __launch_bounds__(256) void scan_final(
    const ushort_t* __restrict__ kvb, const ushort_t* __restrict__ qb,
    const float* __restrict__ decay, const float* __restrict__ P,
    float* __restrict__ out) {
    const int b = blockIdx.x >> 7;
    const int c = (blockIdx.x >> 1) & 63;
    const int dg = blockIdx.x & 1;
    const int d0 = dg * 512 + threadIdx.x * 2;
    const float dc0 = decay[d0], dc1 = decay[d0 + 1];
    const float2 p2 = *(const float2*)&P[((size_t)b * NCHUNK + c) * D_ + d0];
    float m0 = p2.x, m1 = p2.y;
    size_t base = ((size_t)b * T_ + c * CHUNKLEN) * D_ + d0;
#pragma unroll 8
    for (int i = 0; i < CHUNKLEN; ++i) {
        const size_t o = base + (size_t)i * D_;
        ushort2 kv = *(const ushort2*)&kvb[o];
        ushort2 q2 = *(const ushort2*)&qb[o];
        m0 = fmaf(dc0, m0, bf2f(kv.x));
        m1 = fmaf(dc1, m1, bf2f(kv.y));
        *(float2*)&out[o] = make_float2(bf2f(q2.x) * m0, bf2f(q2.y) * m1);
    }
}

extern "C" void kernel_launch(void* const* d_in, const int* in_sizes, int n_in,
                              void* d_out, int out_size, void* d_ws, size_t ws_size,
                              hipStream_t stream) {
    const float* x     = (const float*)d_in[0];
    const float* Wq    = (const float*)d_in[1];
    const float* bq    = (const float*)d_in[2];
    const float* Wk    = (const float*)d_in[3];
    const float* bk    = (const float*)d_in[4];
    const float* Wv    = (const float*)d_in[5];
    const float* bv    = (const float*)d_in[6];
    const float* decay = (const float*)d_in[7];
    float* out = (float*)d_out;

    // workspace carve (~107 MB). S/P alias xb (dead after GEMMs).
    char* ws = (char*)d_ws;
    ushort_t* xb  = (ushort_t*)(ws);                        // 33,554,432 B
    ushort_t* Wb  = (ushort_t*)(ws + 33554432);             //  6,291,456 B
    ushort_t* qb  = (ushort_t*)(ws + 39845888);             // 33,554,432 B
    ushort_t* kvb = (ushort_t*)(ws + 73400320);             // 33,554,432 B
    float*    S   = (float*)(ws);                           //  2 MB (aliases xb)
    float*    P   = (float*)(ws + 2097152);                 //  2 MB (aliases xb)

    ushort_t* Wkb = Wb + D_ * D_;
    ushort_t* Wvb = Wb + 2 * D_ * D_;

    cast_bf16<<<(M_ * D_ / 4 + 255) / 256, 256, 0, stream>>>(x, xb, M_ * D_ / 4);
    cast_w3<<<(3 * D_ * D_ / 4) / 256, 256, 0, stream>>>(Wq, Wk, Wv, Wb);

    dim3 g(M_ / 128, 8);
    gemm_q<<<g, 256, 0, stream>>>(xb, Wb, bq, qb);
    gemm_kv<<<g, 256, 0, stream>>>(xb, Wkb, Wvb, bk, bv, kvb);

    scan_chunks<<<B_ * NCHUNK * 2, 256, 0, stream>>>(kvb, decay, S);
    scan_carry<<<(B_ * D_) / 256, 256, 0, stream>>>(S, decay, P);
    scan_final<<<B_ * NCHUNK * 2, 256, 0, stream>>>(kvb, qb, decay, P, out);
}

// Round 3
// 278.483 us; speedup vs baseline: 1.0923x; 1.0398x over previous
//
#include <hip/hip_runtime.h>
#include <cstdint>

typedef unsigned short ushort_t;
typedef __bf16 bf16x8 __attribute__((ext_vector_type(8)));
typedef float f32x4 __attribute__((ext_vector_type(4)));

#define B_ 8
#define T_ 2048
#define D_ 1024
#define M_ (B_ * T_)        // 16384
#define NCHUNK 64
#define CHUNKLEN 32         // 64*32 = 2048 = T_

__device__ __forceinline__ ushort_t f2bf(float f) {
    union { float f; uint32_t u; } v; v.f = f;
    uint32_t u = v.u;
    uint32_t r = (u + 0x7fffu + ((u >> 16) & 1u)) >> 16;
    return (ushort_t)r;
}
__device__ __forceinline__ float bf2f(ushort_t h) {
    union { uint32_t u; float f; } v; v.u = ((uint32_t)h) << 16;
    return v.f;
}

__device__ __forceinline__ void async16(const ushort_t* g, ushort_t* l) {
    __builtin_amdgcn_global_load_lds(
        (const __attribute__((address_space(1))) void*)g,
        (__attribute__((address_space(3))) void*)l, 16, 0, 0);
}

// ---------------- one-shot cast: x + Wq + Wk + Wv -> bf16 ----------------
__global__ __launch_bounds__(256) void cast_all(
    const float* __restrict__ x, const float* __restrict__ wq,
    const float* __restrict__ wk, const float* __restrict__ wv,
    ushort_t* __restrict__ xb, ushort_t* __restrict__ Wb) {
    const int nx4 = M_ * D_ / 4, nw4 = D_ * D_ / 4;
    int i = blockIdx.x * blockDim.x + threadIdx.x;
    const float* src; ushort_t* dstp; int si;
    if (i < nx4) {
        src = x; si = i; dstp = xb + (size_t)i * 4;
    } else {
        int j = i - nx4;
        dstp = Wb + (size_t)j * 4;
        if (j < nw4)          { src = wq; si = j; }
        else if (j < 2 * nw4) { src = wk; si = j - nw4; }
        else                  { src = wv; si = j - 2 * nw4; }
    }
    float4 v = ((const float4*)src)[si];
    ushort4 o;
    o.x = f2bf(v.x); o.y = f2bf(v.y); o.z = f2bf(v.z); o.w = f2bf(v.w);
    *(ushort4*)dstp = o;
}

// ============ GEMM Q (n-tile 256): q = x @ Wq^T + bq -> bf16 qb ============
// grid (M/128, D/256). Two B-tiles + two acc sets = gemm_kv register profile.
__global__ __launch_bounds__(256, 2) void gemm_q2(
    const ushort_t* __restrict__ xb, const ushort_t* __restrict__ Wq,
    const float* __restrict__ bq, ushort_t* __restrict__ qb) {
    __shared__ ushort_t As[128 * 32];
    __shared__ ushort_t B0[128 * 32];
    __shared__ ushort_t B1[128 * 32];

    const int m0 = blockIdx.x * 128, n0 = blockIdx.y * 256;
    const int t = threadIdx.x;
    const int lane = t & 63, wv = t >> 6;
    const int wr = (wv >> 1) * 64, wc = (wv & 1) * 64;

    f32x4 acc0[4][4], acc1[4][4];
#pragma unroll
    for (int i = 0; i < 4; ++i)
#pragma unroll
        for (int j = 0; j < 4; ++j) {
            acc0[i][j] = (f32x4){0.f, 0.f, 0.f, 0.f};
            acc1[i][j] = (f32x4){0.f, 0.f, 0.f, 0.f};
        }

    const int r0 = t >> 2, r1 = r0 + 64;
    const int sc = ((t & 3) ^ ((r0 >> 1) & 3)) * 8;   // swizzled source col

    const int swq = ((lane & 15) >> 1) & 3;
    const int csel = (((lane >> 4) ^ swq)) * 8;       // swizzled LDS col
    const int rowa = wr + (lane & 15);
    const int rowb = wc + (lane & 15);

    for (int kt = 0; kt < 32; ++kt) {
        const int k0 = kt * 32;
        async16(xb + (size_t)(m0 + r0) * D_ + k0 + sc, &As[t * 8]);
        async16(xb + (size_t)(m0 + r1) * D_ + k0 + sc, &As[(t + 256) * 8]);
        async16(Wq + (size_t)(n0 + r0) * D_ + k0 + sc, &B0[t * 8]);
        async16(Wq + (size_t)(n0 + r1) * D_ + k0 + sc, &B0[(t + 256) * 8]);
        async16(Wq + (size_t)(n0 + 128 + r0) * D_ + k0 + sc, &B1[t * 8]);
        async16(Wq + (size_t)(n0 + 128 + r1) * D_ + k0 + sc, &B1[(t + 256) * 8]);
        __syncthreads();

        bf16x8 af[4], b08[4], b18[4];
#pragma unroll
        for (int i = 0; i < 4; ++i)
            af[i] = *(const bf16x8*)&As[(rowa + i * 16) * 32 + csel];
#pragma unroll
        for (int j = 0; j < 4; ++j) {
            b08[j] = *(const bf16x8*)&B0[(rowb + j * 16) * 32 + csel];
            b18[j] = *(const bf16x8*)&B1[(rowb + j * 16) * 32 + csel];
        }
#pragma unroll
        for (int i = 0; i < 4; ++i)
#pragma unroll
            for (int j = 0; j < 4; ++j) {
                acc0[i][j] = __builtin_amdgcn_mfma_f32_16x16x32_bf16(
                    af[i], b08[j], acc0[i][j], 0, 0, 0);
                acc1[i][j] = __builtin_amdgcn_mfma_f32_16x16x32_bf16(
                    af[i], b18[j], acc1[i][j], 0, 0, 0);
            }
        __syncthreads();
    }

    const int colq = lane & 15;
    const int rowq = (lane >> 4) * 4;
#pragma unroll
    for (int i = 0; i < 4; ++i) {
#pragma unroll
        for (int j = 0; j < 4; ++j) {
            const int cg0 = n0 + wc + j * 16 + colq;
            const int cg1 = cg0 + 128;
            const float bv0 = bq[cg0], bv1 = bq[cg1];
#pragma unroll
            for (int r = 0; r < 4; ++r) {
                const int rg = m0 + wr + i * 16 + rowq + r;
                qb[(size_t)rg * D_ + cg0] = f2bf(acc0[i][j][r] + bv0);
                qb[(size_t)rg * D_ + cg1] = f2bf(acc1[i][j][r] + bv1);
            }
        }
    }
}

// ============ GEMM KV: kv = (x@Wk^T+bk) * (x@Wv^T+bv) -> bf16 kvb ============
__global__ __launch_bounds__(256, 2) void gemm_kv(
    const ushort_t* __restrict__ xb, const ushort_t* __restrict__ Wk,
    const ushort_t* __restrict__ Wv, const float* __restrict__ bk,
    const float* __restrict__ bv, ushort_t* __restrict__ kvb) {
    __shared__ ushort_t As[128 * 32];
    __shared__ ushort_t Bk[128 * 32];
    __shared__ ushort_t Bv[128 * 32];

    const int m0 = blockIdx.x * 128, n0 = blockIdx.y * 128;
    const int t = threadIdx.x;
    const int lane = t & 63, wv = t >> 6;
    const int wr = (wv >> 1) * 64, wc = (wv & 1) * 64;

    f32x4 acck[4][4], accv[4][4];
#pragma unroll
    for (int i = 0; i < 4; ++i)
#pragma unroll
        for (int j = 0; j < 4; ++j) {
            acck[i][j] = (f32x4){0.f, 0.f, 0.f, 0.f};
            accv[i][j] = (f32x4){0.f, 0.f, 0.f, 0.f};
        }

    const int r0 = t >> 2, r1 = r0 + 64;
    const int sc = ((t & 3) ^ ((r0 >> 1) & 3)) * 8;

    const int swq = ((lane & 15) >> 1) & 3;
    const int csel = (((lane >> 4) ^ swq)) * 8;
    const int rowa = wr + (lane & 15);
    const int rowb = wc + (lane & 15);

    for (int kt = 0; kt < 32; ++kt) {
        const int k0 = kt * 32;
        async16(xb + (size_t)(m0 + r0) * D_ + k0 + sc, &As[t * 8]);
        async16(xb + (size_t)(m0 + r1) * D_ + k0 + sc, &As[(t + 256) * 8]);
        async16(Wk + (size_t)(n0 + r0) * D_ + k0 + sc, &Bk[t * 8]);
        async16(Wk + (size_t)(n0 + r1) * D_ + k0 + sc, &Bk[(t + 256) * 8]);
        async16(Wv + (size_t)(n0 + r0) * D_ + k0 + sc, &Bv[t * 8]);
        async16(Wv + (size_t)(n0 + r1) * D_ + k0 + sc, &Bv[(t + 256) * 8]);
        __syncthreads();

        bf16x8 af[4], bk8[4], bv8[4];
#pragma unroll
        for (int i = 0; i < 4; ++i)
            af[i] = *(const bf16x8*)&As[(rowa + i * 16) * 32 + csel];
#pragma unroll
        for (int j = 0; j < 4; ++j) {
            bk8[j] = *(const bf16x8*)&Bk[(rowb + j * 16) * 32 + csel];
            bv8[j] = *(const bf16x8*)&Bv[(rowb + j * 16) * 32 + csel];
        }
#pragma unroll
        for (int i = 0; i < 4; ++i)
#pragma unroll
            for (int j = 0; j < 4; ++j) {
                acck[i][j] = __builtin_amdgcn_mfma_f32_16x16x32_bf16(
                    af[i], bk8[j], acck[i][j], 0, 0, 0);
                accv[i][j] = __builtin_amdgcn_mfma_f32_16x16x32_bf16(
                    af[i], bv8[j], accv[i][j], 0, 0, 0);
            }
        __syncthreads();
    }

    const int colq = lane & 15;
    const int rowq = (lane >> 4) * 4;
#pragma unroll
    for (int i = 0; i < 4; ++i) {
#pragma unroll
        for (int j = 0; j < 4; ++j) {
            const int cg = n0 + wc + j * 16 + colq;
            const float bkv = bk[cg], bvv = bv[cg];
#pragma unroll
            for (int r = 0; r < 4; ++r) {
                const int rg = m0 + wr + i * 16 + rowq + r;
                const float kf = acck[i][j][r] + bkv;
                const float vf = accv[i][j][r] + bvv;
                kvb[(size_t)rg * D_ + cg] = f2bf(kf * vf);
            }
        }
    }
}

// ---------------- scan pass 1: per-chunk local scan -> chunk sum ----------------
// grid = B_*NCHUNK = 512 blocks; 256 threads x 4 channels = 1024 d.
__global__ __launch_bounds__(256) void scan_chunks(
    const ushort_t* __restrict__ kvb, const float* __restrict__ decay,
    float* __restrict__ S) {
    const int b = blockIdx.x >> 6;
    const int c = blockIdx.x & 63;
    const int d0 = threadIdx.x * 4;
    const float4 dc = *(const float4*)&decay[d0];
    float m0 = 0.f, m1 = 0.f, m2 = 0.f, m3 = 0.f;
    size_t base = ((size_t)b * T_ + c * CHUNKLEN) * D_ + d0;
#pragma unroll 8
    for (int i = 0; i < CHUNKLEN; ++i) {
        ushort4 kv = *(const ushort4*)&kvb[base + (size_t)i * D_];
        m0 = fmaf(dc.x, m0, bf2f(kv.x));
        m1 = fmaf(dc.y, m1, bf2f(kv.y));
        m2 = fmaf(dc.z, m2, bf2f(kv.z));
        m3 = fmaf(dc.w, m3, bf2f(kv.w));
    }
    *(float4*)&S[((size_t)b * NCHUNK + c) * D_ + d0] = make_float4(m0, m1, m2, m3);
}

// ---------------- scan pass 2: carry scan across chunks ----------------
__global__ __launch_bounds__(256) void scan_carry(
    const float* __restrict__ S, const float* __restrict__ decay,
    float* __restrict__ P) {
    const int idx = blockIdx.x * blockDim.x + threadIdx.x;  // 8192
    const int d = idx & (D_ - 1), b = idx >> 10;
    const float dec = decay[d];
    float dL = dec;
    dL *= dL; dL *= dL; dL *= dL; dL *= dL; dL *= dL;  // dec^32
    float p = 0.f;
    for (int c = 0; c < NCHUNK; ++c) {
        const size_t o = ((size_t)b * NCHUNK + c) * D_ + d;
        P[o] = p;
        p = fmaf(dL, p, S[o]);
    }
}

// ---------------- scan pass 3: replay with carry, out = q * mem ----------------
__global__ __launch_bounds__(256) void scan_final(
    const ushort_t* __restrict__ kvb, const ushort_t* __restrict__ qb,
    const float* __restrict__ decay, const float* __restrict__ P,
    float* __restrict__ out) {
    const int b = blockIdx.x >> 6;
    const int c = blockIdx.x & 63;
    const int d0 = threadIdx.x * 4;
    const float4 dc = *(const float4*)&decay[d0];
    const float4 p4 = *(const float4*)&P[((size_t)b * NCHUNK + c) * D_ + d0];
    float m0 = p4.x, m1 = p4.y, m2 = p4.z, m3 = p4.w;
    size_t base = ((size_t)b * T_ + c * CHUNKLEN) * D_ + d0;
#pragma unroll 8
    for (int i = 0; i < CHUNKLEN; ++i) {
        const size_t o = base + (size_t)i * D_;
        ushort4 kv = *(const ushort4*)&kvb[o];
        ushort4 q4 = *(const ushort4*)&qb[o];
        m0 = fmaf(dc.x, m0, bf2f(kv.x));
        m1 = fmaf(dc.y, m1, bf2f(kv.y));
        m2 = fmaf(dc.z, m2, bf2f(kv.z));
        m3 = fmaf(dc.w, m3, bf2f(kv.w));
        *(float4*)&out[o] = make_float4(bf2f(q4.x) * m0, bf2f(q4.y) * m1,
                                        bf2f(q4.z) * m2, bf2f(q4.w) * m3);
    }
}

extern "C" void kernel_launch(void* const* d_in, const int* in_sizes, int n_in,
                              void* d_out, int out_size, void* d_ws, size_t ws_size,
                              hipStream_t stream) {
    const float* x     = (const float*)d_in[0];
    const float* Wq    = (const float*)d_in[1];
    const float* bq    = (const float*)d_in[2];
    const float* Wk    = (const float*)d_in[3];
    const float* bk    = (const float*)d_in[4];
    const float* Wv    = (const float*)d_in[5];
    const float* bv    = (const float*)d_in[6];
    const float* decay = (const float*)d_in[7];
    float* out = (float*)d_out;

    // workspace carve (~107 MB). S/P alias xb (dead after GEMMs).
    char* ws = (char*)d_ws;
    ushort_t* xb  = (ushort_t*)(ws);                        // 33,554,432 B
    ushort_t* Wb  = (ushort_t*)(ws + 33554432);             //  6,291,456 B
    ushort_t* qb  = (ushort_t*)(ws + 39845888);             // 33,554,432 B
    ushort_t* kvb = (ushort_t*)(ws + 73400320);             // 33,554,432 B
    float*    S   = (float*)(ws);                           //  2 MB (aliases xb)
    float*    P   = (float*)(ws + 2097152);                 //  2 MB (aliases xb)

    ushort_t* Wqb = Wb;
    ushort_t* Wkb = Wb + D_ * D_;
    ushort_t* Wvb = Wb + 2 * D_ * D_;

    const int ncast = (M_ * D_ / 4) + (3 * D_ * D_ / 4);
    cast_all<<<ncast / 256, 256, 0, stream>>>(x, Wq, Wk, Wv, xb, Wb);

    gemm_q2<<<dim3(M_ / 128, D_ / 256), 256, 0, stream>>>(xb, Wqb, bq, qb);
    gemm_kv<<<dim3(M_ / 128, D_ / 128), 256, 0, stream>>>(xb, Wkb, Wvb, bk, bv, kvb);

    scan_chunks<<<B_ * NCHUNK, 256, 0, stream>>>(kvb, decay, S);
    scan_carry<<<(B_ * D_) / 256, 256, 0, stream>>>(S, decay, P);
    scan_final<<<B_ * NCHUNK, 256, 0, stream>>>(kvb, qb, decay, P, out);
}